// Round 9
// baseline (190.434 us; speedup 1.0000x reference)
//
#include <hip/hip_runtime.h>
#include <math.h>

#define BATCH 2
#define SEQ   2048
#define DM    1024
#define NH    16
#define HD    64
#define MTOT  (BATCH*SEQ)            // 4096

typedef short v8s __attribute__((ext_vector_type(8)));   // 8 bf16 = 4 VGPR
typedef short v4s __attribute__((ext_vector_type(4)));
typedef float v4f __attribute__((ext_vector_type(4)));

#define MFMA16(a, b, c) __builtin_amdgcn_mfma_f32_16x16x32_bf16((a), (b), (c), 0, 0, 0)

__device__ __forceinline__ short f2b(float f) {   // fp32->bf16, round-half-up
    union { float f; unsigned u; } v; v.f = f;
    return (short)((v.u + 0x8000u) >> 16);
}

// raw v_exp_f32 (exp2): OCML exp2f adds a denormal-guard sequence (~6 instr);
// the hot softmax path only needs the HW instruction. exp2(-1e30) -> 0 in HW.
__device__ __forceinline__ float fexp2(float x) {
    float r; asm("v_exp_f32 %0, %1" : "=v"(r) : "v"(x)); return r;
}

// async global->LDS, 16B per lane. dst must be wave-uniform base; HW adds lane*16.
__device__ __forceinline__ void gload16(const void* g, void* lds) {
    __builtin_amdgcn_global_load_lds(
        (const __attribute__((address_space(1))) void*)g,
        (__attribute__((address_space(3))) void*)lds, 16, 0, 0);
}

// native RoPE sincos via revolutions + fract (no library range reduction)
__device__ __forceinline__ void rope_cs(int n, float f_rev, float* c, float* s) {
    float rev = (float)n * f_rev;
    float t = rev - floorf(rev);
    float ang = t * 6.283185307179586f;
    *c = __cosf(ang);
    *s = __sinf(ang);
}

#define L2_1E4_D32 0.4152410118609203f   // log2(10000)/32
#define INV2PI     0.15915494309189535f
#define QSCALE     0.18033688011112042f  // 0.125 * log2(e)

// ---------------------------------------------------------------------------
// Kernel 0: fused fp32 -> bf16 convert for x | Wq | Wk | Wv | Wo into ws base.
// ---------------------------------------------------------------------------
__global__ __launch_bounds__(256) void cvt_all_kernel(
    const float* __restrict__ x,  const float* __restrict__ wq,
    const float* __restrict__ wk, const float* __restrict__ wv,
    const float* __restrict__ wo, short* __restrict__ dst)
{
    int i = blockIdx.x * 256 + threadIdx.x;            // < 1 Mi
    const float* src; int off;
    if (i < (1 << 19)) { src = x; off = i; }
    else {
        int j = i - (1 << 19);
        int wsel = j >> 17;
        off = j & ((1 << 17) - 1);
        src = (wsel == 0) ? wq : (wsel == 1) ? wk : (wsel == 2) ? wv : wo;
    }
    const float4* s4 = (const float4*)src;
    float4 a = s4[2 * off], b = s4[2 * off + 1];
    v8s p;
    p[0] = f2b(a.x); p[1] = f2b(a.y); p[2] = f2b(a.z); p[3] = f2b(a.w);
    p[4] = f2b(b.x); p[5] = f2b(b.y); p[6] = f2b(b.z); p[7] = f2b(b.w);
    *(v8s*)&dst[8 * i] = p;
}

// ---------------------------------------------------------------------------
// Kernel 1: Q/K/V projections, 128x128 MFMA tile. Native-sincos RoPE.
// BK=64: stage both 32-K sub-tiles per barrier pair (round-7, best measured).
// No blockIdx swizzle here: with round-robin dispatch, blocks sharing an
// A-panel (same m, ids differing by 32/256 == 0 mod 8) already land on the
// same XCD — chunked remap would BREAK that locality.
//   z=0: K = RoPE(x @ Wk^T)        -> [bh][key][d]
//   z=1: V = x @ Wv^T (transposed) -> Vt[bh][d][key]
//   z=2: Q = QSCALE*RoPE(x @ Wq^T) -> Qb[bh][row][d]
// grid = (MTOT/128, DM/128, 3) = 768 blocks, 3/CU.
// ---------------------------------------------------------------------------
__global__ __launch_bounds__(256, 3) void qkv_rope_mfma(
    const short* __restrict__ xb, const short* __restrict__ Wqb,
    const short* __restrict__ Wkb, const short* __restrict__ Wvb,
    short* __restrict__ K, short* __restrict__ Vt, short* __restrict__ Qb)
{
    const int zz = blockIdx.z;
    const short* __restrict__ Wb = (zz == 0) ? Wkb : (zz == 1) ? Wvb : Wqb;
    const int m0 = blockIdx.x * 128, e00 = blockIdx.y * 128;
    const int tid = threadIdx.x;
    const int w = tid >> 6, lane = tid & 63, lq = lane >> 4, lr = lane & 15;
    const int wm = w >> 1, wn = w & 1;

    __shared__ union {
        struct { short As[2][128][32]; short Bs[2][128][32]; } p1;  // 32 KB
        short Css[128][136];                                         // 34 KB
    } u;

    v4f acc[4][4];
    #pragma unroll
    for (int i = 0; i < 4; ++i)
        for (int j = 0; j < 4; ++j)
            for (int r = 0; r < 4; ++r) acc[i][j][r] = 0.f;

    const int gr = lane >> 2, gc = 8 * (lane & 3);
    for (int k0 = 0; k0 < DM; k0 += 64) {
        __syncthreads();   // prev iter LDS reads done
        #pragma unroll
        for (int ks = 0; ks < 2; ++ks) {
            gload16(&xb[(size_t)(m0 + 32 * w      + gr) * DM + k0 + 32 * ks + gc],
                    &u.p1.As[ks][32 * w][0]);
            gload16(&xb[(size_t)(m0 + 32 * w + 16 + gr) * DM + k0 + 32 * ks + gc],
                    &u.p1.As[ks][32 * w + 16][0]);
            gload16(&Wb[(size_t)(e00 + 32 * w      + gr) * DM + k0 + 32 * ks + gc],
                    &u.p1.Bs[ks][32 * w][0]);
            gload16(&Wb[(size_t)(e00 + 32 * w + 16 + gr) * DM + k0 + 32 * ks + gc],
                    &u.p1.Bs[ks][32 * w + 16][0]);
        }
        __syncthreads();   // vmcnt drained before barrier -> both sub-tiles visible
        #pragma unroll
        for (int ks = 0; ks < 2; ++ks) {
            v8s af[4], bf[4];
            #pragma unroll
            for (int i = 0; i < 4; ++i)
                af[i] = *(const v8s*)&u.p1.As[ks][64 * wm + 16 * i + lr][8 * lq];
            #pragma unroll
            for (int j = 0; j < 4; ++j)
                bf[j] = *(const v8s*)&u.p1.Bs[ks][64 * wn + 16 * j + lr][8 * lq];
            #pragma unroll
            for (int i = 0; i < 4; ++i)
                #pragma unroll
                for (int j = 0; j < 4; ++j)
                    acc[i][j] = MFMA16(af[i], bf[j], acc[i][j]);
        }
    }
    __syncthreads();   // k-loop LDS reads done before Css overwrite

    const int b = m0 >> 11, n00 = m0 & (SEQ - 1);

    if (zz != 1) {
        // RoPE in-register (cols of this wave = one head; pairs nt <-> nt^2)
        short* __restrict__ dst = (zz == 0) ? K : Qb;
        const float sc = (zz == 0) ? 1.0f : QSCALE;
        float f0 = exp2f(-(float)lr * L2_1E4_D32) * INV2PI;
        float f1 = exp2f(-(float)(16 + lr) * L2_1E4_D32) * INV2PI;
        #pragma unroll
        for (int i = 0; i < 4; ++i) {
            #pragma unroll
            for (int r = 0; r < 4; ++r) {
                int row = 64 * wm + 16 * i + 4 * lq + r;
                int n = n00 + row;
                float c0v, s0v, c1v, s1v;
                rope_cs(n, f0, &c0v, &s0v);
                rope_cs(n, f1, &c1v, &s1v);
                float q0 = acc[i][0][r], q1 = acc[i][1][r];
                float q2 = acc[i][2][r], q3 = acc[i][3][r];
                u.Css[row][64 * wn + lr]      = f2b(sc * (q0 * c0v - q2 * s0v));
                u.Css[row][64 * wn + 16 + lr] = f2b(sc * (q1 * c1v - q3 * s1v));
                u.Css[row][64 * wn + 32 + lr] = f2b(sc * (q2 * c0v + q0 * s0v));
                u.Css[row][64 * wn + 48 + lr] = f2b(sc * (q3 * c1v + q1 * s1v));
            }
        }
        __syncthreads();
        int row = tid >> 1, hh = tid & 1;
        int h = (e00 >> 6) + hh;
        int n = n00 + row;
        size_t base = (((size_t)(b * NH + h)) * SEQ + n) * HD;
        #pragma unroll
        for (int p = 0; p < 8; ++p)
            *(v8s*)&dst[base + 8 * p] = *(const v8s*)&u.Css[row][64 * hh + 8 * p];
    } else {
        // V transposed: Css_T[col][row], packed b64 along row (r contiguous)
        #pragma unroll
        for (int i = 0; i < 4; ++i) {
            #pragma unroll
            for (int j = 0; j < 4; ++j) {
                v4s t;
                #pragma unroll
                for (int r = 0; r < 4; ++r) t[r] = f2b(acc[i][j][r]);
                *(v4s*)&u.Css[64 * wn + 16 * j + lr][64 * wm + 16 * i + 4 * lq] = t;
            }
        }
        __syncthreads();
        int c = tid >> 1, half = (tid & 1) * 64;
        int h = (e00 + c) >> 6, d = (e00 + c) & 63;
        size_t base = (((size_t)(b * NH + h)) * HD + d) * SEQ + n00 + half;
        #pragma unroll
        for (int p = 0; p < 8; ++p)
            *(v8s*)&Vt[base + 8 * p] = *(const v8s*)&u.Css[c][half + 8 * p];
    }
}

// ---------------------------------------------------------------------------
// Kernel 2: flash attention — round-7 body + XCD-chunked block swizzle (T1).
// FETCH_SIZE was 70 MB vs ~26 MB compulsory: 32 blocks share each (b,h)'s
// K/V panel (512 KB) but default round-robin dispatch spreads them over all
// 8 XCDs -> panel pulled into 8 L2s. Remap logical = (i&7)*64 + (i>>3)
// (bijective, 512 = 8*64): XCD k's 64 blocks cover h in {2k,2k+1} x b x m
// -> 4 panels = 2 MB resident in its 4 MB L2 for all re-reads.
// Kept verbatim: T2 XOR-swizzle, key-permuted staging, fixed-max softmax,
// raw v_exp_f32, v_cvt_pk_bf16_f32, register prefetch.
// launch_bounds min-waves MUST stay 4: (512,6) forces spills (round-1).
// Key-split (r5/r6) abandoned: 66KB LDS halved occupancy -> net loss.
// grid = (MTOT/128, NH) = 512 blocks.
// ---------------------------------------------------------------------------
#define SWZ(tile, row, bo) ((char*)&(tile)[row][0] + ((bo) ^ (((row) & 7) << 4)))

__global__ __launch_bounds__(512, 4) void attn_mfma(
    const short* __restrict__ Qb, const short* __restrict__ K,
    const short* __restrict__ Vt, const int* __restrict__ mask,
    short* __restrict__ O)
{
    const int flat = blockIdx.y * 32 + blockIdx.x;      // dispatch-linear id
    const int lg   = (flat & 7) * 64 + (flat >> 3);     // XCD-chunked logical
    const int m0 = (lg & 31) * 128, h = lg >> 5;
    const int b = m0 >> 11, n0 = m0 & (SEQ - 1), bh = b * NH + h;
    const int tid = threadIdx.x;
    const int w = tid >> 6, lane = tid & 63, lq = lane >> 4, lr = lane & 15;

    __shared__ short Ks[128][64];    // 16 KB, XOR-swizzled (key-permuted rows)
    __shared__ short Vs[64][128];    // 16 KB, XOR-swizzled ([d][128 keys])
    __shared__ short Ps[128][64];    // 16 KB, XOR-swizzled (wave-private strips)
    __shared__ float mbias[128];     // 512 B, indexed by permuted storage row

    // ---- load Q A-fragments (rows 16w+lr, pre-scaled + RoPE'd) ----
    const short* __restrict__ Qh = Qb + (size_t)bh * SEQ * HD;
    v8s aq[2];
    #pragma unroll
    for (int ks = 0; ks < 2; ++ks)
        aq[ks] = *(const v8s*)&Qh[(size_t)(n0 + 16 * w + lr) * HD + 32 * ks + 8 * lq];

    float lacc[4] = {0.f, 0.f, 0.f, 0.f};
    v4f o[4];
    #pragma unroll
    for (int nt = 0; nt < 4; ++nt)
        for (int r = 0; r < 4; ++r) o[nt][r] = 0.f;

    // staging indices: K 128 rows x 64 d ; V 64 d x 128 keys
    const int kr = tid >> 2, kc = (tid & 3) * 16;     // kc in shorts (global)
    const int kb = 32 * (tid & 3);                    // LDS byte offset
    const int krh = kr & 63;
    const int pkr = 64 * (kr >> 6) + 16 * (krh & 3) + (krh >> 2);  // permuted
    const int vr = tid >> 3, vc = (tid & 7) * 16;
    const int vb = 32 * (tid & 7);
    const short* __restrict__ Kb = K + (size_t)bh * SEQ * HD;
    const short* __restrict__ Vb = Vt + (size_t)bh * HD * SEQ;

    // prefetch chunk 0
    v8s k1 = *(const v8s*)&Kb[(size_t)kr * HD + kc];
    v8s k2 = *(const v8s*)&Kb[(size_t)kr * HD + kc + 8];
    v8s v1 = *(const v8s*)&Vb[(size_t)vr * SEQ + vc];
    v8s v2 = *(const v8s*)&Vb[(size_t)vr * SEQ + vc + 8];
    int mnext = ((tid & 3) == 0) ? mask[b * SEQ + kr] : 0;

    for (int c0 = 0; c0 < SEQ; c0 += 128) {
        __syncthreads();                      // prev chunk LDS reads done
        *(v8s*)SWZ(Ks, pkr, kb)      = k1;
        *(v8s*)SWZ(Ks, pkr, kb + 16) = k2;
        *(v8s*)SWZ(Vs, vr, vb)       = v1;
        *(v8s*)SWZ(Vs, vr, vb + 16)  = v2;
        if ((tid & 3) == 0) mbias[pkr] = mnext ? -24.0f : -1e30f;
        __syncthreads();
        if (c0 + 128 < SEQ) {                 // prefetch next chunk
            k1 = *(const v8s*)&Kb[(size_t)(c0 + 128 + kr) * HD + kc];
            k2 = *(const v8s*)&Kb[(size_t)(c0 + 128 + kr) * HD + kc + 8];
            v1 = *(const v8s*)&Vb[(size_t)vr * SEQ + c0 + 128 + vc];
            v2 = *(const v8s*)&Vb[(size_t)vr * SEQ + c0 + 128 + vc + 8];
            if ((tid & 3) == 0) mnext = mask[b * SEQ + c0 + 128 + kr];
        }

        #pragma unroll
        for (int half = 0; half < 2; ++half) {
            // hoist K fragments; S col (nt,lr) <-> key 64*half + 4*lr + nt
            v8s kf[2][4];
            #pragma unroll
            for (int ks = 0; ks < 2; ++ks)
                #pragma unroll
                for (int nt = 0; nt < 4; ++nt)
                    kf[ks][nt] = *(const v8s*)SWZ(Ks, 64 * half + 16 * nt + lr,
                                                  64 * ks + 16 * lq);
            float bias[4];
            #pragma unroll
            for (int nt = 0; nt < 4; ++nt)
                bias[nt] = mbias[64 * half + 16 * nt + lr];

            v4f sv[4];
            #pragma unroll
            for (int nt = 0; nt < 4; ++nt)
                for (int r = 0; r < 4; ++r) sv[nt][r] = 0.f;
            #pragma unroll
            for (int ks = 0; ks < 2; ++ks)
                #pragma unroll
                for (int nt = 0; nt < 4; ++nt)
                    sv[nt] = MFMA16(aq[ks], kf[ks][nt], sv[nt]);

            // p = exp2(s + bias); v_cvt_pk packed write (keys 4lr..4lr+3)
            #pragma unroll
            for (int r = 0; r < 4; ++r) {
                float p0 = fexp2(sv[0][r] + bias[0]);
                float p1 = fexp2(sv[1][r] + bias[1]);
                float p2 = fexp2(sv[2][r] + bias[2]);
                float p3 = fexp2(sv[3][r] + bias[3]);
                lacc[r] += (p0 + p1) + (p2 + p3);
                unsigned u0, u1;
                asm("v_cvt_pk_bf16_f32 %0, %1, %2" : "=v"(u0) : "v"(p0), "v"(p1));
                asm("v_cvt_pk_bf16_f32 %0, %1, %2" : "=v"(u1) : "v"(p2), "v"(p3));
                uint2 pk; pk.x = u0; pk.y = u1;
                int prow = 16 * w + 4 * lq + r;
                *(uint2*)SWZ(Ps, prow, 8 * lr) = pk;   // 8B stays within 16B slot
            }
            // O += P @ V_half  (Ps strip wave-private; V cols 64*half+...)
            #pragma unroll
            for (int ks = 0; ks < 2; ++ks) {
                v8s a = *(const v8s*)SWZ(Ps, 16 * w + lr, 64 * ks + 16 * lq);
                #pragma unroll
                for (int nt = 0; nt < 4; ++nt) {
                    v8s vf = *(const v8s*)SWZ(Vs, 16 * nt + lr,
                                              128 * half + 64 * ks + 16 * lq);
                    o[nt] = MFMA16(a, vf, o[nt]);
                }
            }
        }
    }

    // ---- finalize: one butterfly per row; all-masked rows -> l=0 -> 0 ----
    #pragma unroll
    for (int r = 0; r < 4; ++r) {
        float l = lacc[r];
        l += __shfl_xor(l, 1);
        l += __shfl_xor(l, 2);
        l += __shfl_xor(l, 4);
        l += __shfl_xor(l, 8);
        float inv = (l > 0.f) ? 1.f / l : 0.f;
        int qrow = 16 * w + 4 * lq + r;
        #pragma unroll
        for (int nt = 0; nt < 4; ++nt)
            O[(size_t)(m0 + qrow) * DM + h * HD + 16 * nt + lr] =
                f2b(o[nt][r] * inv);
    }
}

// ---------------------------------------------------------------------------
// Kernel 3: out = O @ Wo^T, 64x128 MFMA tile (512 blocks), fp32 store.
// BK=64 (round-7). No swizzle: same-m blocks already co-XCD (id diff 64).
// grid = (MTOT/64, DM/128).
// ---------------------------------------------------------------------------
__global__ __launch_bounds__(256, 2) void oproj_mfma(
    const short* __restrict__ O, const short* __restrict__ Wob,
    float* __restrict__ out)
{
    const int m0 = blockIdx.x * 64, e00 = blockIdx.y * 128;
    const int tid = threadIdx.x;
    const int w = tid >> 6, lane = tid & 63, lq = lane >> 4, lr = lane & 15;

    __shared__ short As[2][64][32];    // 8 KB
    __shared__ short Bs[2][128][32];   // 16 KB

    v4f acc[4][2];
    #pragma unroll
    for (int i = 0; i < 4; ++i)
        for (int j = 0; j < 2; ++j)
            for (int r = 0; r < 4; ++r) acc[i][j][r] = 0.f;

    const int gr = lane >> 2, gc = 8 * (lane & 3);
    for (int k0 = 0; k0 < DM; k0 += 64) {
        __syncthreads();
        #pragma unroll
        for (int ks = 0; ks < 2; ++ks) {
            gload16(&O[(size_t)(m0 + 16 * w + gr) * DM + k0 + 32 * ks + gc],
                    &As[ks][16 * w][0]);
            gload16(&Wob[(size_t)(e00 + 32 * w      + gr) * DM + k0 + 32 * ks + gc],
                    &Bs[ks][32 * w][0]);
            gload16(&Wob[(size_t)(e00 + 32 * w + 16 + gr) * DM + k0 + 32 * ks + gc],
                    &Bs[ks][32 * w + 16][0]);
        }
        __syncthreads();
        #pragma unroll
        for (int ks = 0; ks < 2; ++ks) {
            v8s af[4], bf[2];
            #pragma unroll
            for (int i = 0; i < 4; ++i)
                af[i] = *(const v8s*)&As[ks][16 * i + lr][8 * lq];
            #pragma unroll
            for (int j = 0; j < 2; ++j)
                bf[j] = *(const v8s*)&Bs[ks][32 * w + 16 * j + lr][8 * lq];
            #pragma unroll
            for (int i = 0; i < 4; ++i)
                #pragma unroll
                for (int j = 0; j < 2; ++j)
                    acc[i][j] = MFMA16(af[i], bf[j], acc[i][j]);
        }
    }

    #pragma unroll
    for (int i = 0; i < 4; ++i)
        #pragma unroll
        for (int r = 0; r < 4; ++r) {
            int m = m0 + 16 * i + 4 * lq + r;
            #pragma unroll
            for (int j = 0; j < 2; ++j)
                out[(size_t)m * DM + e00 + 32 * w + 16 * j + lr] = acc[i][j][r];
        }
}

// ---------------------------------------------------------------------------
extern "C" void kernel_launch(void* const* d_in, const int* in_sizes, int n_in,
                              void* d_out, int out_size, void* d_ws, size_t ws_size,
                              hipStream_t stream)
{
    const float* x    = (const float*)d_in[0];
    const int*   mask = (const int*)d_in[1];
    const float* Wq   = (const float*)d_in[2];
    const float* Wk   = (const float*)d_in[3];
    const float* Wv   = (const float*)d_in[4];
    const float* Wo   = (const float*)d_in[5];
    float* out = (float*)d_out;

    // ws (24 MiB of shorts): xb | Wqb | Wkb | Wvb | Wob | Qb
    //   xb region is reused for O after qkv_rope (attn no longer reads x).
    short* xb  = (short*)d_ws;                    // 8 MB (x, then O)
    short* Wqb = xb  + (size_t)MTOT * DM;         // 2 MB each
    short* Wkb = Wqb + (size_t)DM * DM;
    short* Wvb = Wkb + (size_t)DM * DM;
    short* Wob = Wvb + (size_t)DM * DM;
    short* Qb  = Wob + (size_t)DM * DM;           // 8 MB
    short* O   = xb;                              // alias (post-qkv)
    // d_out (16 MiB) doubles as K/Vt scratch until the final projection
    short* K  = (short*)d_out;                    // 8 MB
    short* Vt = K + (size_t)MTOT * DM;            // 8 MB

    cvt_all_kernel<<<4096, 256, 0, stream>>>(x, Wq, Wk, Wv, Wo, xb);

    dim3 g1(MTOT / 128, DM / 128, 3);
    qkv_rope_mfma<<<g1, 256, 0, stream>>>(xb, Wqb, Wkb, Wvb, K, Vt, Qb);

    dim3 g2(MTOT / 128, NH);
    attn_mfma<<<g2, 512, 0, stream>>>(Qb, K, Vt, mask, O);

    dim3 g3(MTOT / 64, DM / 128);
    oproj_mfma<<<g3, 256, 0, stream>>>(O, Wob, out);
}

// Round 10
// 188.533 us; speedup vs baseline: 1.0101x; 1.0101x over previous
//
#include <hip/hip_runtime.h>
#include <math.h>

#define BATCH 2
#define SEQ   2048
#define DM    1024
#define NH    16
#define HD    64
#define MTOT  (BATCH*SEQ)            // 4096

typedef short v8s __attribute__((ext_vector_type(8)));   // 8 bf16 = 4 VGPR
typedef short v4s __attribute__((ext_vector_type(4)));
typedef float v4f __attribute__((ext_vector_type(4)));
typedef float v16f __attribute__((ext_vector_type(16)));

#define MFMA16(a, b, c) __builtin_amdgcn_mfma_f32_16x16x32_bf16((a), (b), (c), 0, 0, 0)
#define MFMA32(a, b, c) __builtin_amdgcn_mfma_f32_32x32x16_bf16((a), (b), (c), 0, 0, 0)

__device__ __forceinline__ short f2b(float f) {   // fp32->bf16, round-half-up
    union { float f; unsigned u; } v; v.f = f;
    return (short)((v.u + 0x8000u) >> 16);
}

// raw v_exp_f32 (exp2): OCML exp2f adds a denormal-guard sequence (~6 instr);
// the hot softmax path only needs the HW instruction. exp2(-1e30) -> 0 in HW.
__device__ __forceinline__ float fexp2(float x) {
    float r; asm("v_exp_f32 %0, %1" : "=v"(r) : "v"(x)); return r;
}

// async global->LDS, 16B per lane. dst must be wave-uniform base; HW adds lane*16.
__device__ __forceinline__ void gload16(const void* g, void* lds) {
    __builtin_amdgcn_global_load_lds(
        (const __attribute__((address_space(1))) void*)g,
        (__attribute__((address_space(3))) void*)lds, 16, 0, 0);
}

// native RoPE sincos via revolutions + fract (no library range reduction)
__device__ __forceinline__ void rope_cs(int n, float f_rev, float* c, float* s) {
    float rev = (float)n * f_rev;
    float t = rev - floorf(rev);
    float ang = t * 6.283185307179586f;
    *c = __cosf(ang);
    *s = __sinf(ang);
}

#define L2_1E4_D32 0.4152410118609203f   // log2(10000)/32
#define INV2PI     0.15915494309189535f
#define QSCALE     0.18033688011112042f  // 0.125 * log2(e)

// ---------------------------------------------------------------------------
// Kernel 0: fused fp32 -> bf16 convert for x | Wq | Wk | Wv | Wo into ws base.
// ---------------------------------------------------------------------------
__global__ __launch_bounds__(256) void cvt_all_kernel(
    const float* __restrict__ x,  const float* __restrict__ wq,
    const float* __restrict__ wk, const float* __restrict__ wv,
    const float* __restrict__ wo, short* __restrict__ dst)
{
    int i = blockIdx.x * 256 + threadIdx.x;            // < 1 Mi
    const float* src; int off;
    if (i < (1 << 19)) { src = x; off = i; }
    else {
        int j = i - (1 << 19);
        int wsel = j >> 17;
        off = j & ((1 << 17) - 1);
        src = (wsel == 0) ? wq : (wsel == 1) ? wk : (wsel == 2) ? wv : wo;
    }
    const float4* s4 = (const float4*)src;
    float4 a = s4[2 * off], b = s4[2 * off + 1];
    v8s p;
    p[0] = f2b(a.x); p[1] = f2b(a.y); p[2] = f2b(a.z); p[3] = f2b(a.w);
    p[4] = f2b(b.x); p[5] = f2b(b.y); p[6] = f2b(b.z); p[7] = f2b(b.w);
    *(v8s*)&dst[8 * i] = p;
}

// ---------------------------------------------------------------------------
// Kernel 1: Q/K/V projections, 128x128 MFMA tile. Native-sincos RoPE.
// BK=64 (round-7 best). Identical to round 9.
//   z=0: K = RoPE(x @ Wk^T)        -> [bh][key][d]
//   z=1: V = x @ Wv^T (transposed) -> Vt[bh][d][key]
//   z=2: Q = QSCALE*RoPE(x @ Wq^T) -> Qb[bh][row][d]
// grid = (MTOT/128, DM/128, 3) = 768 blocks, 3/CU.
// ---------------------------------------------------------------------------
__global__ __launch_bounds__(256, 3) void qkv_rope_mfma(
    const short* __restrict__ xb, const short* __restrict__ Wqb,
    const short* __restrict__ Wkb, const short* __restrict__ Wvb,
    short* __restrict__ K, short* __restrict__ Vt, short* __restrict__ Qb)
{
    const int zz = blockIdx.z;
    const short* __restrict__ Wb = (zz == 0) ? Wkb : (zz == 1) ? Wvb : Wqb;
    const int m0 = blockIdx.x * 128, e00 = blockIdx.y * 128;
    const int tid = threadIdx.x;
    const int w = tid >> 6, lane = tid & 63, lq = lane >> 4, lr = lane & 15;
    const int wm = w >> 1, wn = w & 1;

    __shared__ union {
        struct { short As[2][128][32]; short Bs[2][128][32]; } p1;  // 32 KB
        short Css[128][136];                                         // 34 KB
    } u;

    v4f acc[4][4];
    #pragma unroll
    for (int i = 0; i < 4; ++i)
        for (int j = 0; j < 4; ++j)
            for (int r = 0; r < 4; ++r) acc[i][j][r] = 0.f;

    const int gr = lane >> 2, gc = 8 * (lane & 3);
    for (int k0 = 0; k0 < DM; k0 += 64) {
        __syncthreads();   // prev iter LDS reads done
        #pragma unroll
        for (int ks = 0; ks < 2; ++ks) {
            gload16(&xb[(size_t)(m0 + 32 * w      + gr) * DM + k0 + 32 * ks + gc],
                    &u.p1.As[ks][32 * w][0]);
            gload16(&xb[(size_t)(m0 + 32 * w + 16 + gr) * DM + k0 + 32 * ks + gc],
                    &u.p1.As[ks][32 * w + 16][0]);
            gload16(&Wb[(size_t)(e00 + 32 * w      + gr) * DM + k0 + 32 * ks + gc],
                    &u.p1.Bs[ks][32 * w][0]);
            gload16(&Wb[(size_t)(e00 + 32 * w + 16 + gr) * DM + k0 + 32 * ks + gc],
                    &u.p1.Bs[ks][32 * w + 16][0]);
        }
        __syncthreads();   // vmcnt drained before barrier -> both sub-tiles visible
        #pragma unroll
        for (int ks = 0; ks < 2; ++ks) {
            v8s af[4], bf[4];
            #pragma unroll
            for (int i = 0; i < 4; ++i)
                af[i] = *(const v8s*)&u.p1.As[ks][64 * wm + 16 * i + lr][8 * lq];
            #pragma unroll
            for (int j = 0; j < 4; ++j)
                bf[j] = *(const v8s*)&u.p1.Bs[ks][64 * wn + 16 * j + lr][8 * lq];
            #pragma unroll
            for (int i = 0; i < 4; ++i)
                #pragma unroll
                for (int j = 0; j < 4; ++j)
                    acc[i][j] = MFMA16(af[i], bf[j], acc[i][j]);
        }
    }
    __syncthreads();   // k-loop LDS reads done before Css overwrite

    const int b = m0 >> 11, n00 = m0 & (SEQ - 1);

    if (zz != 1) {
        // RoPE in-register (cols of this wave = one head; pairs nt <-> nt^2)
        short* __restrict__ dst = (zz == 0) ? K : Qb;
        const float sc = (zz == 0) ? 1.0f : QSCALE;
        float f0 = exp2f(-(float)lr * L2_1E4_D32) * INV2PI;
        float f1 = exp2f(-(float)(16 + lr) * L2_1E4_D32) * INV2PI;
        #pragma unroll
        for (int i = 0; i < 4; ++i) {
            #pragma unroll
            for (int r = 0; r < 4; ++r) {
                int row = 64 * wm + 16 * i + 4 * lq + r;
                int n = n00 + row;
                float c0v, s0v, c1v, s1v;
                rope_cs(n, f0, &c0v, &s0v);
                rope_cs(n, f1, &c1v, &s1v);
                float q0 = acc[i][0][r], q1 = acc[i][1][r];
                float q2 = acc[i][2][r], q3 = acc[i][3][r];
                u.Css[row][64 * wn + lr]      = f2b(sc * (q0 * c0v - q2 * s0v));
                u.Css[row][64 * wn + 16 + lr] = f2b(sc * (q1 * c1v - q3 * s1v));
                u.Css[row][64 * wn + 32 + lr] = f2b(sc * (q2 * c0v + q0 * s0v));
                u.Css[row][64 * wn + 48 + lr] = f2b(sc * (q3 * c1v + q1 * s1v));
            }
        }
        __syncthreads();
        int row = tid >> 1, hh = tid & 1;
        int h = (e00 >> 6) + hh;
        int n = n00 + row;
        size_t base = (((size_t)(b * NH + h)) * SEQ + n) * HD;
        #pragma unroll
        for (int p = 0; p < 8; ++p)
            *(v8s*)&dst[base + 8 * p] = *(const v8s*)&u.Css[row][64 * hh + 8 * p];
    } else {
        // V transposed: Css_T[col][row], packed b64 along row (r contiguous)
        #pragma unroll
        for (int i = 0; i < 4; ++i) {
            #pragma unroll
            for (int j = 0; j < 4; ++j) {
                v4s t;
                #pragma unroll
                for (int r = 0; r < 4; ++r) t[r] = f2b(acc[i][j][r]);
                *(v4s*)&u.Css[64 * wn + 16 * j + lr][64 * wm + 16 * i + 4 * lq] = t;
            }
        }
        __syncthreads();
        int c = tid >> 1, half = (tid & 1) * 64;
        int h = (e00 + c) >> 6, d = (e00 + c) & 63;
        size_t base = (((size_t)(b * NH + h)) * HD + d) * SEQ + n00 + half;
        #pragma unroll
        for (int p = 0; p < 8; ++p)
            *(v8s*)&Vt[base + 8 * p] = *(const v8s*)&u.Css[c][half + 8 * p];
    }
}

// ---------------------------------------------------------------------------
// Kernel 2: flash attention, 32x32x16 MFMA (round-10 rewrite).
// Diagnosis held across rounds 3-9: LDS-pipe-bound (HBM 4.8% after T1 swizzle,
// MfmaUtil 23%). 32x32 MFMA feeds 32k FLOP per 16B fragment vs 16k for 16x16:
// 4 waves x 32 Q-rows each (block still 128 rows), per-work K/V fragment LDS
// traffic HALVES. Swapped QK^T: S' = mfma(A=K, B=Q) -> lane holds qrow=l&31,
// 16 keys (reg&3)+8*(reg>>2)+4*hi. P packed per reg-quad (4 consecutive keys)
// as 8B writes into per-wave strip Ps[w][32 q][40] (80B stride: b128 reads
// conflict-free, 8B writes ~4-way minor). PV: A=P strip, B=Vs cols.
// Softmax: fixed-max M=24; wave-uniform allvalid fast path (bias scalar);
// general per-key slow path kept for masked inputs. Denom: lane-local sum +
// shfl_xor(32) + linv gather at end. T1 XCD swizzle kept (FETCH 70->13MB).
// LDS 44 KB -> 3 blocks/CU x 4 waves = 12 waves/CU.
// launch_bounds(256,2): 256-VGPR cap (round-1/5 lesson: tight caps spill;
// WRITE_SIZE >> 9216 KB next round = spill alarm -> abort).
// grid = (MTOT/128, NH) = 512 blocks x 256 threads.
// ---------------------------------------------------------------------------
#define SWZ(tile, row, bo) ((char*)&(tile)[row][0] + ((bo) ^ (((row) & 7) << 4)))

__global__ __launch_bounds__(256, 2) void attn_mfma(
    const short* __restrict__ Qb, const short* __restrict__ K,
    const short* __restrict__ Vt, const int* __restrict__ mask,
    short* __restrict__ O)
{
    const int flat = blockIdx.y * 32 + blockIdx.x;      // dispatch-linear id
    const int lg   = (flat & 7) * 64 + (flat >> 3);     // XCD-chunked logical
    const int m0 = (lg & 31) * 128, h = lg >> 5;
    const int b = m0 >> 11, n0 = m0 & (SEQ - 1), bh = b * NH + h;
    const int tid = threadIdx.x;
    const int w = tid >> 6, lane = tid & 63;
    const int l31 = lane & 31, hi = lane >> 5;

    __shared__ short Ks[128][64];    // 16 KB, XOR-swizzled, key-major (no perm)
    __shared__ short Vs[64][128];    // 16 KB, XOR-swizzled ([d][128 keys])
    __shared__ short Ps[4][32][40];  // 10 KB, per-wave P strips (80B rows)
    __shared__ float mbias[128];     // 512 B, per-key bias
    __shared__ float linv[128];      // 512 B, per-qrow 1/denom

    // ---- Q B-fragments: wave's 32 rows; lane: qcol=l31, d-elems 8*hi ----
    const short* __restrict__ Qh = Qb + (size_t)bh * SEQ * HD;
    v8s qf[4];
    #pragma unroll
    for (int ds = 0; ds < 4; ++ds)
        qf[ds] = *(const v8s*)&Qh[(size_t)(n0 + 32 * w + l31) * HD + 16 * ds + 8 * hi];

    v16f o0, o1;
    #pragma unroll
    for (int r = 0; r < 16; ++r) { o0[r] = 0.f; o1[r] = 0.f; }
    float lacc = 0.f;

    // staging: K 128 rows x 64 d (2 thr/row); V 64 d x 128 keys (4 thr/row)
    const int kr2 = tid >> 1, kc2 = (tid & 1) * 32;   // shorts
    const int vr2 = tid >> 2, vc2 = (tid & 3) * 32;
    const short* __restrict__ Kb = K + (size_t)bh * SEQ * HD;
    const short* __restrict__ Vb = Vt + (size_t)bh * HD * SEQ;

    v8s kpre[4], vpre[4];
    #pragma unroll
    for (int j = 0; j < 4; ++j) {
        kpre[j] = *(const v8s*)&Kb[(size_t)kr2 * HD + kc2 + 8 * j];
        vpre[j] = *(const v8s*)&Vb[(size_t)vr2 * SEQ + vc2 + 8 * j];
    }
    int mnext = (tid < 128) ? mask[b * SEQ + tid] : 0;

    for (int c0 = 0; c0 < SEQ; c0 += 128) {
        __syncthreads();                      // prev chunk LDS reads done
        #pragma unroll
        for (int j = 0; j < 4; ++j) {
            *(v8s*)SWZ(Ks, kr2, 2 * kc2 + 16 * j) = kpre[j];
            *(v8s*)SWZ(Vs, vr2, 2 * vc2 + 16 * j) = vpre[j];
        }
        if (tid < 128) mbias[tid] = mnext ? -24.0f : -1e30f;
        __syncthreads();
        if (c0 + 128 < SEQ) {                 // prefetch next chunk
            #pragma unroll
            for (int j = 0; j < 4; ++j) {
                kpre[j] = *(const v8s*)&Kb[(size_t)(c0 + 128 + kr2) * HD + kc2 + 8 * j];
                vpre[j] = *(const v8s*)&Vb[(size_t)vr2 * SEQ + c0 + 128 + vc2 + 8 * j];
            }
            if (tid < 128) mnext = mask[b * SEQ + c0 + 128 + tid];
        }

        // wave-uniform fast-path test: all 128 keys of this chunk valid?
        float mb0 = mbias[lane], mb1 = mbias[64 + lane];
        int allv = __all(mb0 > -1e29f && mb1 > -1e29f);

        #pragma unroll
        for (int kt = 0; kt < 4; ++kt) {
            // A = K fragment: row key = l31 (+32kt), d-elems 8*hi in 16-slice
            v8s kf[4];
            #pragma unroll
            for (int ds = 0; ds < 4; ++ds)
                kf[ds] = *(const v8s*)SWZ(Ks, 32 * kt + l31, 32 * ds + 16 * hi);

            v16f s;
            #pragma unroll
            for (int r = 0; r < 16; ++r) s[r] = 0.f;
            #pragma unroll
            for (int ds = 0; ds < 4; ++ds)
                s = MFMA32(kf[ds], qf[ds], s);

            // softmax: reg 4g+j <-> key 8g+j+4hi (j=0..3 consecutive)
            if (allv) {
                #pragma unroll
                for (int g = 0; g < 4; ++g) {
                    float p0 = fexp2(s[4 * g + 0] - 24.0f);
                    float p1 = fexp2(s[4 * g + 1] - 24.0f);
                    float p2 = fexp2(s[4 * g + 2] - 24.0f);
                    float p3 = fexp2(s[4 * g + 3] - 24.0f);
                    lacc += (p0 + p1) + (p2 + p3);
                    unsigned u0, u1;
                    asm("v_cvt_pk_bf16_f32 %0, %1, %2" : "=v"(u0) : "v"(p0), "v"(p1));
                    asm("v_cvt_pk_bf16_f32 %0, %1, %2" : "=v"(u1) : "v"(p2), "v"(p3));
                    uint2 pk; pk.x = u0; pk.y = u1;
                    *(uint2*)&Ps[w][l31][8 * g + 4 * hi] = pk;
                }
            } else {
                #pragma unroll
                for (int g = 0; g < 4; ++g) {
                    float p0 = fexp2(s[4 * g + 0] + mbias[32 * kt + 8 * g + 4 * hi + 0]);
                    float p1 = fexp2(s[4 * g + 1] + mbias[32 * kt + 8 * g + 4 * hi + 1]);
                    float p2 = fexp2(s[4 * g + 2] + mbias[32 * kt + 8 * g + 4 * hi + 2]);
                    float p3 = fexp2(s[4 * g + 3] + mbias[32 * kt + 8 * g + 4 * hi + 3]);
                    lacc += (p0 + p1) + (p2 + p3);
                    unsigned u0, u1;
                    asm("v_cvt_pk_bf16_f32 %0, %1, %2" : "=v"(u0) : "v"(p0), "v"(p1));
                    asm("v_cvt_pk_bf16_f32 %0, %1, %2" : "=v"(u1) : "v"(p2), "v"(p3));
                    uint2 pk; pk.x = u0; pk.y = u1;
                    *(uint2*)&Ps[w][l31][8 * g + 4 * hi] = pk;
                }
            }

            // PV: O[32q][64d] += P[32q][32k] @ V[32k][64d], K-slices of 16
            #pragma unroll
            for (int ks = 0; ks < 2; ++ks) {
                v8s pa = *(const v8s*)&Ps[w][l31][16 * ks + 8 * hi];
                v8s vf0 = *(const v8s*)SWZ(Vs, l31,      64 * kt + 32 * ks + 16 * hi);
                v8s vf1 = *(const v8s*)SWZ(Vs, l31 + 32, 64 * kt + 32 * ks + 16 * hi);
                o0 = MFMA32(pa, vf0, o0);
                o1 = MFMA32(pa, vf1, o1);
            }
        }
    }

    // ---- denom: merge hi-halves (lane l & l+32 share qrow l31) ----
    lacc += __shfl_xor(lacc, 32);
    float inv = (lacc > 0.f) ? 1.f / lacc : 0.f;   // all-masked rows -> 0
    if (lane < 32) linv[32 * w + l31] = inv;
    // wave-internal LDS write->read; compiler inserts lgkmcnt
    #pragma unroll
    for (int r = 0; r < 16; ++r) {
        const int q = (r & 3) + 8 * (r >> 2);
        float iv = linv[32 * w + q + 4 * hi];
        size_t base = (size_t)(m0 + 32 * w + q + 4 * hi) * DM + h * HD + l31;
        O[base]      = f2b(o0[r] * iv);
        O[base + 32] = f2b(o1[r] * iv);
    }
}

// ---------------------------------------------------------------------------
// Kernel 3: out = O @ Wo^T, 64x128 MFMA tile (512 blocks), fp32 store.
// BK=64 (round-7). Identical to round 9.
// grid = (MTOT/64, DM/128).
// ---------------------------------------------------------------------------
__global__ __launch_bounds__(256, 2) void oproj_mfma(
    const short* __restrict__ O, const short* __restrict__ Wob,
    float* __restrict__ out)
{
    const int m0 = blockIdx.x * 64, e00 = blockIdx.y * 128;
    const int tid = threadIdx.x;
    const int w = tid >> 6, lane = tid & 63, lq = lane >> 4, lr = lane & 15;

    __shared__ short As[2][64][32];    // 8 KB
    __shared__ short Bs[2][128][32];   // 16 KB

    v4f acc[4][2];
    #pragma unroll
    for (int i = 0; i < 4; ++i)
        for (int j = 0; j < 2; ++j)
            for (int r = 0; r < 4; ++r) acc[i][j][r] = 0.f;

    const int gr = lane >> 2, gc = 8 * (lane & 3);
    for (int k0 = 0; k0 < DM; k0 += 64) {
        __syncthreads();
        #pragma unroll
        for (int ks = 0; ks < 2; ++ks) {
            gload16(&O[(size_t)(m0 + 16 * w + gr) * DM + k0 + 32 * ks + gc],
                    &As[ks][16 * w][0]);
            gload16(&Wob[(size_t)(e00 + 32 * w      + gr) * DM + k0 + 32 * ks + gc],
                    &Bs[ks][32 * w][0]);
            gload16(&Wob[(size_t)(e00 + 32 * w + 16 + gr) * DM + k0 + 32 * ks + gc],
                    &Bs[ks][32 * w + 16][0]);
        }
        __syncthreads();
        #pragma unroll
        for (int ks = 0; ks < 2; ++ks) {
            v8s af[4], bf[2];
            #pragma unroll
            for (int i = 0; i < 4; ++i)
                af[i] = *(const v8s*)&As[ks][16 * i + lr][8 * lq];
            #pragma unroll
            for (int j = 0; j < 2; ++j)
                bf[j] = *(const v8s*)&Bs[ks][32 * w + 16 * j + lr][8 * lq];
            #pragma unroll
            for (int i = 0; i < 4; ++i)
                #pragma unroll
                for (int j = 0; j < 2; ++j)
                    acc[i][j] = MFMA16(af[i], bf[j], acc[i][j]);
        }
    }

    #pragma unroll
    for (int i = 0; i < 4; ++i)
        #pragma unroll
        for (int r = 0; r < 4; ++r) {
            int m = m0 + 16 * i + 4 * lq + r;
            #pragma unroll
            for (int j = 0; j < 2; ++j)
                out[(size_t)m * DM + e00 + 32 * w + 16 * j + lr] = acc[i][j][r];
        }
}

// ---------------------------------------------------------------------------
extern "C" void kernel_launch(void* const* d_in, const int* in_sizes, int n_in,
                              void* d_out, int out_size, void* d_ws, size_t ws_size,
                              hipStream_t stream)
{
    const float* x    = (const float*)d_in[0];
    const int*   mask = (const int*)d_in[1];
    const float* Wq   = (const float*)d_in[2];
    const float* Wk   = (const float*)d_in[3];
    const float* Wv   = (const float*)d_in[4];
    const float* Wo   = (const float*)d_in[5];
    float* out = (float*)d_out;

    // ws (24 MiB of shorts): xb | Wqb | Wkb | Wvb | Wob | Qb
    //   xb region is reused for O after qkv_rope (attn no longer reads x).
    short* xb  = (short*)d_ws;                    // 8 MB (x, then O)
    short* Wqb = xb  + (size_t)MTOT * DM;         // 2 MB each
    short* Wkb = Wqb + (size_t)DM * DM;
    short* Wvb = Wkb + (size_t)DM * DM;
    short* Wob = Wvb + (size_t)DM * DM;
    short* Qb  = Wob + (size_t)DM * DM;           // 8 MB
    short* O   = xb;                              // alias (post-qkv)
    // d_out (16 MiB) doubles as K/Vt scratch until the final projection
    short* K  = (short*)d_out;                    // 8 MB
    short* Vt = K + (size_t)MTOT * DM;            // 8 MB

    cvt_all_kernel<<<4096, 256, 0, stream>>>(x, Wq, Wk, Wv, Wo, xb);

    dim3 g1(MTOT / 128, DM / 128, 3);
    qkv_rope_mfma<<<g1, 256, 0, stream>>>(xb, Wqb, Wkb, Wvb, K, Vt, Qb);

    dim3 g2(MTOT / 128, NH);
    attn_mfma<<<g2, 256, 0, stream>>>(Qb, K, Vt, mask, O);

    dim3 g3(MTOT / 64, DM / 128);
    oproj_mfma<<<g3, 256, 0, stream>>>(O, Wob, out);
}